// Round 3
// baseline (137.558 us; speedup 1.0000x reference)
//
#include <hip/hip_runtime.h>
#include <stdint.h>

#define N_WORDS 8192
#define LOG2E_8 0.18033688011112043f   // log2(e)/sqrt(64)

typedef __attribute__((ext_vector_type(8))) short short8;
typedef __attribute__((ext_vector_type(4))) float f32x4;
typedef __attribute__((ext_vector_type(4))) _Float16 half4;

__device__ __forceinline__ unsigned short f32_to_bf16(float f) {
    union { float f; unsigned u; } v; v.f = f;
    unsigned u = v.u;
    return (unsigned short)((u + 0x7FFFu + ((u >> 16) & 1u)) >> 16);
}

__device__ __forceinline__ unsigned short f32_to_f16(float f) {
    union { _Float16 h; unsigned short u; } cv;
    cv.h = (_Float16)f;
    return cv.u;
}

// global -> LDS direct copy, 16B per lane. LDS dest is wave-uniform base;
// HW adds lane*16. Global ptr is per-lane.
__device__ __forceinline__ void async16(const void* g, void* l) {
    __builtin_amdgcn_global_load_lds(
        (const __attribute__((address_space(1))) unsigned int*)g,
        (__attribute__((address_space(3))) unsigned int*)l, 16, 0, 0);
}

// ---------------------------------------------------------------------------
// Kernel A: x f32 -> bf16, chunk-swizzled: chunk c (8 elems) of row r stored
// at position (c & ~7) | ((c ^ (r&7)) & 7). One thread per 8-elem chunk.
// ---------------------------------------------------------------------------
__global__ __launch_bounds__(256) void xcvt_kernel(
    const float* __restrict__ x, unsigned short* __restrict__ xb)
{
    int ci = blockIdx.x * 256 + threadIdx.x;   // 0 .. 8192*64-1
    int row = ci >> 6, c = ci & 63;
    const float* src = x + ((size_t)row * 512 + c * 8);
    float4 v0 = *(const float4*)(src);
    float4 v1 = *(const float4*)(src + 4);
    unsigned u0 = f32_to_bf16(v0.x) | ((unsigned)f32_to_bf16(v0.y) << 16);
    unsigned u1 = f32_to_bf16(v0.z) | ((unsigned)f32_to_bf16(v0.w) << 16);
    unsigned u2 = f32_to_bf16(v1.x) | ((unsigned)f32_to_bf16(v1.y) << 16);
    unsigned u3 = f32_to_bf16(v1.z) | ((unsigned)f32_to_bf16(v1.w) << 16);
    int dst = (c & ~7) | ((c ^ (row & 7)) & 7);
    *(uint4*)(xb + (size_t)row * 512 + dst * 8) = make_uint4(u0, u1, u2, u3);
}

// ---------------------------------------------------------------------------
// Kernel B: wT[n][k] = w{q,k,v}[k][n] as bf16, [192][512], chunk-swizzled by
// (n&7). Rows 0..63 (wq) pre-scaled by log2e/8 (folds softmax scale+base).
// grid 64 blocks (one k-chunk each) x 192 threads (one n each).
// ---------------------------------------------------------------------------
__global__ __launch_bounds__(192) void wprep_kernel(
    const float* __restrict__ wq, const float* __restrict__ wk,
    const float* __restrict__ wv, unsigned short* __restrict__ wT)
{
    int n = threadIdx.x;           // 0..191
    int c = blockIdx.x;            // k-chunk 0..63
    const float* w = (n < 64) ? wq : (n < 128) ? wk : wv;
    int col = n & 63;
    float scale = (n < 64) ? LOG2E_8 : 1.0f;
    unsigned short o[8];
#pragma unroll
    for (int j = 0; j < 8; ++j)
        o[j] = f32_to_bf16(w[(size_t)(c * 8 + j) * 64 + col] * scale);
    unsigned u0 = o[0] | ((unsigned)o[1] << 16);
    unsigned u1 = o[2] | ((unsigned)o[3] << 16);
    unsigned u2 = o[4] | ((unsigned)o[5] << 16);
    unsigned u3 = o[6] | ((unsigned)o[7] << 16);
    int dst = (c & ~7) | ((c ^ (n & 7)) & 7);
    *(uint4*)(wT + (size_t)n * 512 + dst * 8) = make_uint4(u0, u1, u2, u3);
}

// ---------------------------------------------------------------------------
// Kernel C: w_o_eff[p][j] = sum_h w_o[h*64+p][j]   (64 x 512 f32)
// ---------------------------------------------------------------------------
__global__ __launch_bounds__(256) void woeff_kernel(
    const float* __restrict__ wo, float* __restrict__ we)
{
    int i = blockIdx.x * 256 + threadIdx.x;
    int p = i >> 9;
    int j = i & 511;
    float s = 0.0f;
#pragma unroll
    for (int h = 0; h < 8; ++h) s += wo[(size_t)(h * 64 + p) * 512 + j];
    we[i] = s;
}

// ---------------------------------------------------------------------------
// Kernel D: QKV GEMM [8192x512] @ [512x192], bf16 MFMA, double-buffered
// global_load_lds staging. 512 blocks x 16 m-rows; wave w handles n-cols
// [w*48, w*48+48) (3 n-tiles). Outputs qB/kB (row-major, chunk-swizzled)
// and vH ([vcol][row], row-group swizzled) as in the attention layouts.
// ---------------------------------------------------------------------------
__global__ __launch_bounds__(256) void qkv_gemm(
    const unsigned short* __restrict__ xb,
    const unsigned short* __restrict__ wT,
    unsigned short* __restrict__ qB, unsigned short* __restrict__ kB,
    unsigned short* __restrict__ vH)
{
    __shared__ __align__(16) unsigned short ldsX[2][16 * 64];
    __shared__ __align__(16) unsigned short ldsW[2][192 * 64];

    int t = threadIdx.x;
    int wvid = t >> 6, lane = t & 63;
    int lq = lane & 15, quad = lane >> 4;
    int m0 = blockIdx.x * 16;

    f32x4 acc[3];
#pragma unroll
    for (int v = 0; v < 3; ++v) acc[v] = (f32x4){0.f, 0.f, 0.f, 0.f};

    auto stage = [&](int kb, int buf) {
        int k0 = kb * 64;
        if (wvid < 2) {
            int L = wvid * 64 + lane;          // 0..127
            int row = m0 + (L >> 3), ct = L & 7;
            const char* src = (const char*)xb + ((size_t)row * 512 + k0) * 2 + ct * 16;
            async16(src, (char*)(&ldsX[buf][0]) + (size_t)(wvid * 64) * 16);
        }
#pragma unroll
        for (int i = 0; i < 6; ++i) {
            int L0 = (i * 4 + wvid) * 64;      // wave-uniform
            int L = L0 + lane;                  // 0..1535
            int n = L >> 3, ct = L & 7;
            const char* src = (const char*)wT + ((size_t)n * 512 + k0) * 2 + ct * 16;
            async16(src, (char*)(&ldsW[buf][0]) + (size_t)L0 * 16);
        }
    };

    stage(0, 0);
    for (int kb = 0; kb < 8; ++kb) {
        __syncthreads();
        if (kb < 7) stage(kb + 1, (kb + 1) & 1);
        const unsigned short* Xb = &ldsX[kb & 1][0];
        const unsigned short* Wb = &ldsW[kb & 1][0];
        int s7m = lq & 7;   // (m0+lq)&7 == lq&7 since m0 % 16 == 0
        short8 a0 = *(const short8*)(Xb + lq * 64 + ((quad ^ s7m) << 3));
        short8 a1 = *(const short8*)(Xb + lq * 64 + (((4 + quad) ^ s7m) << 3));
#pragma unroll
        for (int v = 0; v < 3; ++v) {
            int n = (wvid * 3 + v) * 16 + lq;
            const unsigned short* wr = Wb + n * 64;
            int s7 = n & 7;
            short8 b0 = *(const short8*)(wr + ((quad ^ s7) << 3));
            short8 b1 = *(const short8*)(wr + (((4 + quad) ^ s7) << 3));
            acc[v] = __builtin_amdgcn_mfma_f32_16x16x32_bf16(a0, b0, acc[v], 0, 0, 0);
            acc[v] = __builtin_amdgcn_mfma_f32_16x16x32_bf16(a1, b1, acc[v], 0, 0, 0);
        }
    }

#pragma unroll
    for (int v = 0; v < 3; ++v) {
        int n = (wvid * 3 + v) * 16 + lq;
#pragma unroll
        for (int r = 0; r < 4; ++r) {
            int row = m0 + quad * 4 + r;
            float val = acc[v][r];
            if (n < 64) {
                int col = ((((n >> 3) ^ (row & 7)) << 3)) | (n & 7);
                qB[(size_t)row * 64 + col] = f32_to_bf16(val);
            } else if (n < 128) {
                int c = n - 64;
                int col = ((((c >> 3) ^ (row & 7)) << 3)) | (c & 7);
                kB[(size_t)row * 64 + col] = f32_to_bf16(val);
            } else {
                int c = n - 128;
                int rs = (row & ~63) | (((((row >> 3) & 7) ^ (c & 7)) << 3)) | (row & 7);
                vH[(size_t)c * N_WORDS + rs] = f32_to_f16(val);
            }
        }
    }
}

// ---------------------------------------------------------------------------
// Kernel E: fixed-max flash attention partials, double-buffered 64-row tiles.
// grid (64 q-blocks of 128 rows, S splits), 256 thr = 4 waves x 32 qrows.
// S^T = K.Q^T via 16x16x32 bf16 MFMA; C-layout is directly the A-fragment of
// the 16x16x16 f16 PV MFMA. p = exp2(s_raw) (Q pre-scaled; fixed max safe).
// ---------------------------------------------------------------------------
__global__ __launch_bounds__(256) void attn_kernel(
    const unsigned short* __restrict__ qB,
    const unsigned short* __restrict__ kB,
    const unsigned short* __restrict__ vH,
    float* __restrict__ pO, float* __restrict__ pl, int nk)
{
    __shared__ __align__(16) unsigned short ldsK[2][64 * 64];  // [krow][dim swz]
    __shared__ __align__(16) unsigned short ldsV[2][64 * 64];  // [vcol][krow swz]

    int t = threadIdx.x;
    int wvid = t >> 6, lane = t & 63;
    int lq = lane & 15, quad = lane >> 4;
    int mbase = blockIdx.x * 128 + wvid * 32;
    int n0 = blockIdx.y * nk;

    short8 qf[2][2];
#pragma unroll
    for (int qs = 0; qs < 2; ++qs) {
        int row = mbase + qs * 16 + lq;
        const unsigned short* qr = qB + (size_t)row * 64;
        int s7 = row & 7;
        qf[qs][0] = *(const short8*)(qr + ((quad ^ s7) << 3));
        qf[qs][1] = *(const short8*)(qr + (((4 + quad) ^ s7) << 3));
    }

    f32x4 oacc[2][4];
#pragma unroll
    for (int qs = 0; qs < 2; ++qs)
#pragma unroll
        for (int vt = 0; vt < 4; ++vt) oacc[qs][vt] = (f32x4){0.f, 0.f, 0.f, 0.f};
    float lsum0 = 0.f, lsum1 = 0.f;

    auto stage = [&](int tile, int buf) {
        int nb = n0 + tile * 64;
        const char* gK = (const char*)kB + (size_t)nb * 128;
#pragma unroll
        for (int i = 0; i < 2; ++i) {
            int L0 = (wvid * 2 + i) * 64;
            async16(gK + (size_t)(L0 + lane) * 16, (char*)(&ldsK[buf][0]) + (size_t)L0 * 16);
        }
#pragma unroll
        for (int i = 0; i < 2; ++i) {
            int L0 = (wvid * 2 + i) * 64;
            int L = L0 + lane;
            int vcol = L >> 3, ct = L & 7;
            const char* src = (const char*)vH + (size_t)vcol * 16384 + (size_t)nb * 2 + ct * 16;
            async16(src, (char*)(&ldsV[buf][0]) + (size_t)L0 * 16);
        }
    };

    int tiles = nk >> 6;
    stage(0, 0);
    for (int tt = 0; tt < tiles; ++tt) {
        __syncthreads();                       // buf[tt&1] staged; buf[(tt+1)&1] free
        if (tt + 1 < tiles) stage(tt + 1, (tt + 1) & 1);
        const unsigned short* Kb = &ldsK[tt & 1][0];
        const unsigned short* Vb = &ldsV[tt & 1][0];

#pragma unroll
        for (int nt = 0; nt < 4; ++nt) {
            int s7 = lq & 7;
            const unsigned short* kr = Kb + (nt * 16 + lq) * 64;
            short8 a0 = *(const short8*)(kr + ((quad ^ s7) << 3));
            short8 a1 = *(const short8*)(kr + (((4 + quad) ^ s7) << 3));
            f32x4 st0 = (f32x4){0.f, 0.f, 0.f, 0.f};
            f32x4 st1 = (f32x4){0.f, 0.f, 0.f, 0.f};
            st0 = __builtin_amdgcn_mfma_f32_16x16x32_bf16(a0, qf[0][0], st0, 0, 0, 0);
            st0 = __builtin_amdgcn_mfma_f32_16x16x32_bf16(a1, qf[0][1], st0, 0, 0, 0);
            st1 = __builtin_amdgcn_mfma_f32_16x16x32_bf16(a0, qf[1][0], st1, 0, 0, 0);
            st1 = __builtin_amdgcn_mfma_f32_16x16x32_bf16(a1, qf[1][1], st1, 0, 0, 0);

            half4 p0, p1;
#pragma unroll
            for (int r = 0; r < 4; ++r) {
                float e = exp2f(st0[r]);
                lsum0 += e;
                p0[r] = (_Float16)e;
            }
#pragma unroll
            for (int r = 0; r < 4; ++r) {
                float e = exp2f(st1[r]);
                lsum1 += e;
                p1[r] = (_Float16)e;
            }

            int j2 = nt * 2 + (quad >> 1);
            int off = (quad & 1) * 4;
#pragma unroll
            for (int vt = 0; vt < 4; ++vt) {
                int vcol = vt * 16 + lq;
                int p = j2 ^ (vcol & 7);
                half4 vb = *(const half4*)(Vb + vcol * 64 + (p << 3) + off);
                oacc[0][vt] = __builtin_amdgcn_mfma_f32_16x16x16f16(p0, vb, oacc[0][vt], 0, 0, 0);
                oacc[1][vt] = __builtin_amdgcn_mfma_f32_16x16x16f16(p1, vb, oacc[1][vt], 0, 0, 0);
            }
        }
    }

    lsum0 += __shfl_xor(lsum0, 16); lsum0 += __shfl_xor(lsum0, 32);
    lsum1 += __shfl_xor(lsum1, 16); lsum1 += __shfl_xor(lsum1, 32);

    size_t obase = (size_t)blockIdx.y * N_WORDS;
    if (quad == 0) {
        pl[obase + mbase + lq] = lsum0;
        pl[obase + mbase + 16 + lq] = lsum1;
    }
#pragma unroll
    for (int qs = 0; qs < 2; ++qs)
#pragma unroll
        for (int vt = 0; vt < 4; ++vt)
#pragma unroll
            for (int r = 0; r < 4; ++r) {
                int row = mbase + qs * 16 + quad * 4 + r;
                pO[(obase + row) * 64 + vt * 16 + lq] = oacc[qs][vt][r];
            }
}

// ---------------------------------------------------------------------------
// Kernel F: fused combine + output GEMM. 512 blocks x 16 rows.
// head rows built from S split partials (normalized), then head @ w_o_eff.
// ---------------------------------------------------------------------------
__global__ __launch_bounds__(256) void out_kernel(
    const float* __restrict__ pO, const float* __restrict__ pl,
    const float* __restrict__ we, float* __restrict__ out, int S)
{
    __shared__ __align__(16) float ldsHT[64 * 16];  // [k][row]
    __shared__ float ldsL[16];
    int t = threadIdx.x;
    int r0 = blockIdx.x * 16;
    int r = t >> 4, c4 = (t & 15) * 4;

    float4 a = make_float4(0.f, 0.f, 0.f, 0.f);
    for (int s = 0; s < S; ++s) {
        float4 pv = *(const float4*)(pO + ((size_t)s * N_WORDS + r0 + r) * 64 + c4);
        a.x += pv.x; a.y += pv.y; a.z += pv.z; a.w += pv.w;
    }
    if (t < 16) {
        float lr = 0.f;
        for (int s = 0; s < S; ++s) lr += pl[(size_t)s * N_WORDS + r0 + t];
        ldsL[t] = lr;
    }
    __syncthreads();
    float inv = 1.0f / ldsL[r];
    ldsHT[(c4 + 0) * 16 + r] = a.x * inv;
    ldsHT[(c4 + 1) * 16 + r] = a.y * inv;
    ldsHT[(c4 + 2) * 16 + r] = a.z * inv;
    ldsHT[(c4 + 3) * 16 + r] = a.w * inv;
    __syncthreads();

    int w = t >> 6, l = t & 63;
    int cg = w & 1, rg = w >> 1;
    int j0 = cg * 256 + l * 4;

    float4 acc[8];
#pragma unroll
    for (int rr = 0; rr < 8; ++rr) acc[rr] = make_float4(0.f, 0.f, 0.f, 0.f);

    for (int k = 0; k < 64; ++k) {
        float4 wv = *(const float4*)(we + (size_t)k * 512 + j0);
        float4 h0 = *(const float4*)(ldsHT + k * 16 + rg * 8);
        float4 h1 = *(const float4*)(ldsHT + k * 16 + rg * 8 + 4);
        float hr[8] = {h0.x, h0.y, h0.z, h0.w, h1.x, h1.y, h1.z, h1.w};
#pragma unroll
        for (int rr = 0; rr < 8; ++rr) {
            acc[rr].x = fmaf(hr[rr], wv.x, acc[rr].x);
            acc[rr].y = fmaf(hr[rr], wv.y, acc[rr].y);
            acc[rr].z = fmaf(hr[rr], wv.z, acc[rr].z);
            acc[rr].w = fmaf(hr[rr], wv.w, acc[rr].w);
        }
    }

#pragma unroll
    for (int rr = 0; rr < 8; ++rr) {
        int row = r0 + rg * 8 + rr;
        *(float4*)(out + (size_t)row * 512 + j0) = acc[rr];
    }
}

// ---------------------------------------------------------------------------
extern "C" void kernel_launch(void* const* d_in, const int* in_sizes, int n_in,
                              void* d_out, int out_size, void* d_ws, size_t ws_size,
                              hipStream_t stream)
{
    const float* x  = (const float*)d_in[0];
    const float* wq = (const float*)d_in[1];
    const float* wk = (const float*)d_in[2];
    const float* wv = (const float*)d_in[3];
    const float* wo = (const float*)d_in[4];
    float* out = (float*)d_out;

    char* ws = (char*)d_ws;
    unsigned short* xb = (unsigned short*)(ws);                 // 8 MB
    unsigned short* wT = (unsigned short*)(ws + 8388608);       // 192 KB
    float* we = (float*)(ws + 8585216);                         // 128 KB
    float* pl = (float*)(ws + 8716288);                         // <=256 KB
    unsigned short* qB = (unsigned short*)(ws + 8978432);       // 1 MB
    unsigned short* kB = (unsigned short*)(ws + 10027008);      // 1 MB
    unsigned short* vH = (unsigned short*)(ws + 11075584);      // 1 MB
    float* pO = (float*)(ws + 12124160);                        // S * 2 MB

    int S = (ws_size >= (size_t)12124160 + 8u * 2097152u) ? 8 : 4;
    int nk = N_WORDS / S;

    hipLaunchKernelGGL(xcvt_kernel, dim3(2048), dim3(256), 0, stream, x, xb);
    hipLaunchKernelGGL(wprep_kernel, dim3(64), dim3(192), 0, stream, wq, wk, wv, wT);
    hipLaunchKernelGGL(woeff_kernel, dim3(128), dim3(256), 0, stream, wo, we);
    hipLaunchKernelGGL(qkv_gemm, dim3(512), dim3(256), 0, stream, xb, wT, qB, kB, vH);
    hipLaunchKernelGGL(attn_kernel, dim3(64, S), dim3(256), 0, stream,
                       qB, kB, vH, pO, pl, nk);
    hipLaunchKernelGGL(out_kernel, dim3(512), dim3(256), 0, stream,
                       pO, pl, we, out, S);
}

// Round 5
// 137.246 us; speedup vs baseline: 1.0023x; 1.0023x over previous
//
#include <hip/hip_runtime.h>
#include <stdint.h>

#define N_WORDS 8192
#define LOG2E_8 0.18033688011112043f   // log2(e)/sqrt(64)

typedef __attribute__((ext_vector_type(8))) short short8;
typedef __attribute__((ext_vector_type(4))) float f32x4;
typedef __attribute__((ext_vector_type(4))) _Float16 half4;

__device__ __forceinline__ unsigned short f32_to_bf16(float f) {
    union { float f; unsigned u; } v; v.f = f;
    unsigned u = v.u;
    return (unsigned short)((u + 0x7FFFu + ((u >> 16) & 1u)) >> 16);
}

__device__ __forceinline__ unsigned short f32_to_f16(float f) {
    union { _Float16 h; unsigned short u; } cv;
    cv.h = (_Float16)f;
    return cv.u;
}

// global -> LDS direct copy, 16B per lane. LDS dest is wave-uniform base;
// HW adds lane*16. Global ptr is per-lane.
__device__ __forceinline__ void async16(const void* g, void* l) {
    __builtin_amdgcn_global_load_lds(
        (const __attribute__((address_space(1))) unsigned int*)g,
        (__attribute__((address_space(3))) unsigned int*)l, 16, 0, 0);
}

__device__ __forceinline__ short8 pack_bf16x8(float4 a, float4 b) {
    short8 r;
    r[0] = (short)f32_to_bf16(a.x); r[1] = (short)f32_to_bf16(a.y);
    r[2] = (short)f32_to_bf16(a.z); r[3] = (short)f32_to_bf16(a.w);
    r[4] = (short)f32_to_bf16(b.x); r[5] = (short)f32_to_bf16(b.y);
    r[6] = (short)f32_to_bf16(b.z); r[7] = (short)f32_to_bf16(b.w);
    return r;
}

// ---------------------------------------------------------------------------
// Kernel 1 (fused prep): blocks [0,48) -> wT, blocks [48,176) -> we.
//  wT[n][k] = w{q,k,v}[k][n] bf16 [192][512], chunk-swizzled by n&7;
//            rows 0..63 (wq) pre-scaled by log2e/8.
//  we[p][j] = sum_h wo[h*64+p][j]  (64x512 f32).
// ---------------------------------------------------------------------------
__global__ __launch_bounds__(256) void prep_kernel(
    const float* __restrict__ wq, const float* __restrict__ wk,
    const float* __restrict__ wv, const float* __restrict__ wo,
    unsigned short* __restrict__ wT, float* __restrict__ we)
{
    int b = blockIdx.x, t = threadIdx.x;
    if (b < 48) {
        int job = b * 256 + t;          // 0..12287
        int n = job >> 6, c = job & 63; // n: output row, c: k-chunk
        const float* w = (n < 64) ? wq : (n < 128) ? wk : wv;
        int col = n & 63;
        float scale = (n < 64) ? LOG2E_8 : 1.0f;
        unsigned short o[8];
#pragma unroll
        for (int j = 0; j < 8; ++j)
            o[j] = f32_to_bf16(w[(size_t)(c * 8 + j) * 64 + col] * scale);
        unsigned u0 = o[0] | ((unsigned)o[1] << 16);
        unsigned u1 = o[2] | ((unsigned)o[3] << 16);
        unsigned u2 = o[4] | ((unsigned)o[5] << 16);
        unsigned u3 = o[6] | ((unsigned)o[7] << 16);
        int dst = (c & ~7) | ((c ^ (n & 7)) & 7);
        *(uint4*)(wT + (size_t)n * 512 + dst * 8) = make_uint4(u0, u1, u2, u3);
    } else {
        int i = (b - 48) * 256 + t;     // 0..32767
        int p = i >> 9, j = i & 511;
        float s = 0.0f;
#pragma unroll
        for (int h = 0; h < 8; ++h) s += wo[(size_t)(h * 64 + p) * 512 + j];
        we[i] = s;
    }
}

// ---------------------------------------------------------------------------
// Kernel 2: QKV GEMM [8192x512] @ [512x192], bf16 MFMA, double-buffered
// global_load_lds staging. 256 blocks x 32 m-rows; wave w covers n-cols
// [w*48, w*48+48). x staged as raw f32 (16B-chunk XOR swizzle baked into the
// async16 source index), converted to bf16 at frag read. Outputs qB/kB
// (row-major, chunk-swizzled) and vH ([vcol][row], row-group swizzled).
// ---------------------------------------------------------------------------
__global__ __launch_bounds__(256) void qkv_gemm(
    const float* __restrict__ x,
    const unsigned short* __restrict__ wT,
    unsigned short* __restrict__ qB, unsigned short* __restrict__ kB,
    unsigned short* __restrict__ vH)
{
    __shared__ __align__(16) float ldsX[2][32 * 64];            // 8KB each
    __shared__ __align__(16) unsigned short ldsW[2][192 * 64];  // 24.5KB each

    int t = threadIdx.x;
    int wvid = t >> 6, lane = t & 63;
    int lq = lane & 15, quad = lane >> 4;
    int m0 = blockIdx.x * 32;

    f32x4 acc[3][2];
#pragma unroll
    for (int v = 0; v < 3; ++v)
#pragma unroll
        for (int qs = 0; qs < 2; ++qs) acc[v][qs] = (f32x4){0.f, 0.f, 0.f, 0.f};

    auto stage = [&](int kb, int buf) {
        int k0 = kb * 64;
        // X: 32 rows x 16 chunks (16B) = 512 chunks; 2 async16 per wave
#pragma unroll
        for (int i = 0; i < 2; ++i) {
            int L0 = (wvid * 2 + i) * 64;
            int L = L0 + lane;
            int row = L >> 4, cslot = L & 15;
            int cg = (cslot & 8) | ((cslot ^ (row & 7)) & 7);
            const char* src = (const char*)(x + (size_t)(m0 + row) * 512 + k0) + cg * 16;
            async16(src, (char*)(&ldsX[buf][0]) + (size_t)L0 * 16);
        }
        // W: 192 rows x 8 chunks = 1536 chunks; 6 async16 per wave
#pragma unroll
        for (int i = 0; i < 6; ++i) {
            int L0 = (i * 4 + wvid) * 64;
            int L = L0 + lane;
            int n = L >> 3, ct = L & 7;
            const char* src = (const char*)wT + ((size_t)n * 512 + k0) * 2 + ct * 16;
            async16(src, (char*)(&ldsW[buf][0]) + (size_t)L0 * 16);
        }
    };

    stage(0, 0);
    for (int kb = 0; kb < 8; ++kb) {
        __syncthreads();
        if (kb < 7) stage(kb + 1, (kb + 1) & 1);
        const float4* Xb = (const float4*)(&ldsX[kb & 1][0]);   // row pitch 16
        const unsigned short* Wb = &ldsW[kb & 1][0];
        int s7 = lq & 7;

        short8 af[2][2];
#pragma unroll
        for (int qs = 0; qs < 2; ++qs) {
            int lr = qs * 16 + lq;
            int c0 = (2 * quad) ^ s7;
            float4 x0 = Xb[lr * 16 + c0];
            float4 x1 = Xb[lr * 16 + (c0 ^ 1)];
            float4 x2 = Xb[lr * 16 + (8 | c0)];
            float4 x3 = Xb[lr * 16 + ((8 | c0) ^ 1)];
            af[qs][0] = pack_bf16x8(x0, x1);
            af[qs][1] = pack_bf16x8(x2, x3);
        }
#pragma unroll
        for (int v = 0; v < 3; ++v) {
            int n = (wvid * 3 + v) * 16 + lq;
            const unsigned short* wr = Wb + n * 64;
            int s7n = n & 7;
            short8 b0 = *(const short8*)(wr + ((quad ^ s7n) << 3));
            short8 b1 = *(const short8*)(wr + (((4 + quad) ^ s7n) << 3));
#pragma unroll
            for (int qs = 0; qs < 2; ++qs) {
                acc[v][qs] = __builtin_amdgcn_mfma_f32_16x16x32_bf16(af[qs][0], b0, acc[v][qs], 0, 0, 0);
                acc[v][qs] = __builtin_amdgcn_mfma_f32_16x16x32_bf16(af[qs][1], b1, acc[v][qs], 0, 0, 0);
            }
        }
    }

#pragma unroll
    for (int v = 0; v < 3; ++v) {
        int n = (wvid * 3 + v) * 16 + lq;
#pragma unroll
        for (int qs = 0; qs < 2; ++qs)
#pragma unroll
            for (int r = 0; r < 4; ++r) {
                int row = m0 + qs * 16 + quad * 4 + r;
                float val = acc[v][qs][r];
                if (n < 64) {
                    int col = ((((n >> 3) ^ (row & 7)) << 3)) | (n & 7);
                    qB[(size_t)row * 64 + col] = f32_to_bf16(val);
                } else if (n < 128) {
                    int c = n - 64;
                    int col = ((((c >> 3) ^ (row & 7)) << 3)) | (c & 7);
                    kB[(size_t)row * 64 + col] = f32_to_bf16(val);
                } else {
                    int c = n - 128;
                    int rs = (row & ~63) | (((((row >> 3) & 7) ^ (c & 7)) << 3)) | (row & 7);
                    vH[(size_t)c * N_WORDS + rs] = f32_to_f16(val);
                }
            }
    }
}

// ---------------------------------------------------------------------------
// Kernel 3: fixed-max flash attention partials, double-buffered 64-row tiles.
// grid (64 q-blocks of 128 rows, S splits), 256 thr = 4 waves x 32 qrows.
// S^T = K.Q^T via 16x16x32 bf16 MFMA; C-layout is directly the A-fragment of
// the 16x16x16 f16 PV MFMA. p = exp2(s_raw) (Q pre-scaled; fixed max safe).
// ---------------------------------------------------------------------------
__global__ __launch_bounds__(256) void attn_kernel(
    const unsigned short* __restrict__ qB,
    const unsigned short* __restrict__ kB,
    const unsigned short* __restrict__ vH,
    float* __restrict__ pO, float* __restrict__ pl, int nk)
{
    __shared__ __align__(16) unsigned short ldsK[2][64 * 64];  // [krow][dim swz]
    __shared__ __align__(16) unsigned short ldsV[2][64 * 64];  // [vcol][krow swz]

    int t = threadIdx.x;
    int wvid = t >> 6, lane = t & 63;
    int lq = lane & 15, quad = lane >> 4;
    int mbase = blockIdx.x * 128 + wvid * 32;
    int n0 = blockIdx.y * nk;

    short8 qf[2][2];
#pragma unroll
    for (int qs = 0; qs < 2; ++qs) {
        int row = mbase + qs * 16 + lq;
        const unsigned short* qr = qB + (size_t)row * 64;
        int s7 = row & 7;
        qf[qs][0] = *(const short8*)(qr + ((quad ^ s7) << 3));
        qf[qs][1] = *(const short8*)(qr + (((4 + quad) ^ s7) << 3));
    }

    f32x4 oacc[2][4];
#pragma unroll
    for (int qs = 0; qs < 2; ++qs)
#pragma unroll
        for (int vt = 0; vt < 4; ++vt) oacc[qs][vt] = (f32x4){0.f, 0.f, 0.f, 0.f};
    float lsum0 = 0.f, lsum1 = 0.f;

    auto stage = [&](int tile, int buf) {
        int nb = n0 + tile * 64;
        const char* gK = (const char*)kB + (size_t)nb * 128;
#pragma unroll
        for (int i = 0; i < 2; ++i) {
            int L0 = (wvid * 2 + i) * 64;
            async16(gK + (size_t)(L0 + lane) * 16, (char*)(&ldsK[buf][0]) + (size_t)L0 * 16);
        }
#pragma unroll
        for (int i = 0; i < 2; ++i) {
            int L0 = (wvid * 2 + i) * 64;
            int L = L0 + lane;
            int vcol = L >> 3, ct = L & 7;
            const char* src = (const char*)vH + (size_t)vcol * 16384 + (size_t)nb * 2 + ct * 16;
            async16(src, (char*)(&ldsV[buf][0]) + (size_t)L0 * 16);
        }
    };

    int tiles = nk >> 6;
    stage(0, 0);
    for (int tt = 0; tt < tiles; ++tt) {
        __syncthreads();                       // buf[tt&1] staged; other free
        if (tt + 1 < tiles) stage(tt + 1, (tt + 1) & 1);
        const unsigned short* Kb = &ldsK[tt & 1][0];
        const unsigned short* Vb = &ldsV[tt & 1][0];

#pragma unroll
        for (int nt = 0; nt < 4; ++nt) {
            int s7 = lq & 7;
            const unsigned short* kr = Kb + (nt * 16 + lq) * 64;
            short8 a0 = *(const short8*)(kr + ((quad ^ s7) << 3));
            short8 a1 = *(const short8*)(kr + (((4 + quad) ^ s7) << 3));
            f32x4 st0 = (f32x4){0.f, 0.f, 0.f, 0.f};
            f32x4 st1 = (f32x4){0.f, 0.f, 0.f, 0.f};
            st0 = __builtin_amdgcn_mfma_f32_16x16x32_bf16(a0, qf[0][0], st0, 0, 0, 0);
            st0 = __builtin_amdgcn_mfma_f32_16x16x32_bf16(a1, qf[0][1], st0, 0, 0, 0);
            st1 = __builtin_amdgcn_mfma_f32_16x16x32_bf16(a0, qf[1][0], st1, 0, 0, 0);
            st1 = __builtin_amdgcn_mfma_f32_16x16x32_bf16(a1, qf[1][1], st1, 0, 0, 0);

            half4 p0, p1;
#pragma unroll
            for (int r = 0; r < 4; ++r) {
                float e = exp2f(st0[r]);
                lsum0 += e;
                p0[r] = (_Float16)e;
            }
#pragma unroll
            for (int r = 0; r < 4; ++r) {
                float e = exp2f(st1[r]);
                lsum1 += e;
                p1[r] = (_Float16)e;
            }

            int j2 = nt * 2 + (quad >> 1);
            int off = (quad & 1) * 4;
#pragma unroll
            for (int vt = 0; vt < 4; ++vt) {
                int vcol = vt * 16 + lq;
                int p = j2 ^ (vcol & 7);
                half4 vb = *(const half4*)(Vb + vcol * 64 + (p << 3) + off);
                oacc[0][vt] = __builtin_amdgcn_mfma_f32_16x16x16f16(p0, vb, oacc[0][vt], 0, 0, 0);
                oacc[1][vt] = __builtin_amdgcn_mfma_f32_16x16x16f16(p1, vb, oacc[1][vt], 0, 0, 0);
            }
        }
    }

    lsum0 += __shfl_xor(lsum0, 16); lsum0 += __shfl_xor(lsum0, 32);
    lsum1 += __shfl_xor(lsum1, 16); lsum1 += __shfl_xor(lsum1, 32);

    size_t obase = (size_t)blockIdx.y * N_WORDS;
    if (quad == 0) {
        pl[obase + mbase + lq] = lsum0;
        pl[obase + mbase + 16 + lq] = lsum1;
    }
#pragma unroll
    for (int qs = 0; qs < 2; ++qs)
#pragma unroll
        for (int vt = 0; vt < 4; ++vt)
#pragma unroll
            for (int r = 0; r < 4; ++r) {
                int row = mbase + qs * 16 + quad * 4 + r;
                pO[(obase + row) * 64 + vt * 16 + lq] = oacc[qs][vt][r];
            }
}

// ---------------------------------------------------------------------------
// Kernel 4: fused combine + output GEMM. 512 blocks x 16 rows.
// head rows built from S split partials (normalized), then head @ w_o_eff.
// ---------------------------------------------------------------------------
__global__ __launch_bounds__(256) void out_kernel(
    const float* __restrict__ pO, const float* __restrict__ pl,
    const float* __restrict__ we, float* __restrict__ out, int S)
{
    __shared__ __align__(16) float ldsHT[64 * 16];  // [k][row]
    __shared__ float ldsL[16];
    int t = threadIdx.x;
    int r0 = blockIdx.x * 16;
    int r = t >> 4, c4 = (t & 15) * 4;

    float4 a = make_float4(0.f, 0.f, 0.f, 0.f);
    for (int s = 0; s < S; ++s) {
        float4 pv = *(const float4*)(pO + ((size_t)s * N_WORDS + r0 + r) * 64 + c4);
        a.x += pv.x; a.y += pv.y; a.z += pv.z; a.w += pv.w;
    }
    if (t < 16) {
        float lr = 0.f;
        for (int s = 0; s < S; ++s) lr += pl[(size_t)s * N_WORDS + r0 + t];
        ldsL[t] = lr;
    }
    __syncthreads();
    float inv = 1.0f / ldsL[r];
    ldsHT[(c4 + 0) * 16 + r] = a.x * inv;
    ldsHT[(c4 + 1) * 16 + r] = a.y * inv;
    ldsHT[(c4 + 2) * 16 + r] = a.z * inv;
    ldsHT[(c4 + 3) * 16 + r] = a.w * inv;
    __syncthreads();

    int w = t >> 6, l = t & 63;
    int cg = w & 1, rg = w >> 1;
    int j0 = cg * 256 + l * 4;

    float4 acc[8];
#pragma unroll
    for (int rr = 0; rr < 8; ++rr) acc[rr] = make_float4(0.f, 0.f, 0.f, 0.f);

    for (int k = 0; k < 64; ++k) {
        float4 wv = *(const float4*)(we + (size_t)k * 512 + j0);
        float4 h0 = *(const float4*)(ldsHT + k * 16 + rg * 8);
        float4 h1 = *(const float4*)(ldsHT + k * 16 + rg * 8 + 4);
        float hr[8] = {h0.x, h0.y, h0.z, h0.w, h1.x, h1.y, h1.z, h1.w};
#pragma unroll
        for (int rr = 0; rr < 8; ++rr) {
            acc[rr].x = fmaf(hr[rr], wv.x, acc[rr].x);
            acc[rr].y = fmaf(hr[rr], wv.y, acc[rr].y);
            acc[rr].z = fmaf(hr[rr], wv.z, acc[rr].z);
            acc[rr].w = fmaf(hr[rr], wv.w, acc[rr].w);
        }
    }

#pragma unroll
    for (int rr = 0; rr < 8; ++rr) {
        int row = r0 + rg * 8 + rr;
        *(float4*)(out + (size_t)row * 512 + j0) = acc[rr];
    }
}

// ---------------------------------------------------------------------------
extern "C" void kernel_launch(void* const* d_in, const int* in_sizes, int n_in,
                              void* d_out, int out_size, void* d_ws, size_t ws_size,
                              hipStream_t stream)
{
    const float* x  = (const float*)d_in[0];
    const float* wq = (const float*)d_in[1];
    const float* wk = (const float*)d_in[2];
    const float* wv = (const float*)d_in[3];
    const float* wo = (const float*)d_in[4];
    float* out = (float*)d_out;

    char* ws = (char*)d_ws;
    unsigned short* wT = (unsigned short*)(ws);                 // 192 KB
    float* we = (float*)(ws + 196608);                          // 128 KB
    float* pl = (float*)(ws + 327680);                          // 512 KB (S<=16)
    unsigned short* qB = (unsigned short*)(ws + 851968);        // 1 MB
    unsigned short* kB = (unsigned short*)(ws + 1900544);       // 1 MB
    unsigned short* vH = (unsigned short*)(ws + 2949120);       // 1 MB
    float* pO = (float*)(ws + 3997696);                         // S * 2 MB

    int S = (ws_size >= (size_t)3997696 + 16u * 2097152u) ? 16 : 8;
    int nk = N_WORDS / S;

    hipLaunchKernelGGL(prep_kernel, dim3(176), dim3(256), 0, stream,
                       wq, wk, wv, wo, wT, we);
    hipLaunchKernelGGL(qkv_gemm, dim3(256), dim3(256), 0, stream,
                       x, wT, qB, kB, vH);
    hipLaunchKernelGGL(attn_kernel, dim3(64, S), dim3(256), 0, stream,
                       qB, kB, vH, pO, pl, nk);
    hipLaunchKernelGGL(out_kernel, dim3(512), dim3(256), 0, stream,
                       pO, pl, we, out, S);
}